// Round 9
// baseline (240.359 us; speedup 1.0000x reference)
//
#include <hip/hip_runtime.h>
#include <hip/hip_bf16.h>

// ---------------------------------------------------------------------------
// WaveletNauralNet: 9-level DWT -> 8 band reconstructions (h: 2048x32768,
// linear in x1) -> relu -> W0 (181x32768) -> relu -> W1 (13x181) -> relu ->
// W2 (10x13).
//   K1: fused [per-row analysis (d2..d9 via LDS, single d1 drain)] +
//       [W0 fp32->fp16 convert] heterogeneous grid
//   K2: per-(row,L) synthesis, template<L>-specialized cascade (R8 form)
//   K3: split-K MFMA fp16 GEMM (BM=128,BN=192,BK=64), nsplit=64, FP16
//       partials -> grid 1024 = 4 blocks/CU (R7's occupancy) with R8's
//       P traffic (50 MB round-trip). R6: 1/CU latency-bound 66us;
//       R7: fp32 P 200MB evicted A from L3, HBM-bound 100us.
//   K4: reduce fp16 partials + MLP layers 1..2
// ---------------------------------------------------------------------------

typedef _Float16 f16x8 __attribute__((ext_vector_type(8)));
typedef _Float16 f16x4v __attribute__((ext_vector_type(4)));
typedef float f32x4 __attribute__((ext_vector_type(4)));

#define WV_THREADS 256
#define DROW 4144   // per-row float stride of packed d1..d9
#define NSPLIT 64
#define KCHUNK 512

// reconstruction filters
#define L0 0.23037781330885523f
#define L1 0.7148465705525415f
#define L2f 0.6308807679295904f
#define L3 -0.02798376941698385f
#define L4 -0.18703481171888114f
#define L5 0.030841381835986965f
#define L6 0.032883011666982945f
#define L7 -0.010597401784997278f

#define H0 -0.010597401784997278f
#define H1 -0.032883011666982945f
#define H2 0.030841381835986965f
#define H3 0.18703481171888114f
#define H4 -0.02798376941698385f
#define H5 -0.6308807679295904f
#define H6 0.7148465705525415f
#define H7 -0.23037781330885523f

__constant__ constexpr int cNL[10]   = {4096, 2051, 1029, 518, 262, 134, 70, 38, 22, 14};
__constant__ constexpr int cDOFF[10] = {0, 0, 2052, 3082, 3600, 3862, 3996, 4066, 4104, 4126};

__device__ __forceinline__ int ext_idx(int j, int n) {
  return (j < 6) ? (5 - j) : ((j < n + 6) ? (j - 6) : (2 * n + 5 - j));
}

// one DWT level, 2 outputs per thread, stride-1 lanes.
__device__ __forceinline__ void dwt2(const float* a, float* anext, float* d,
                                     int n, int m, bool store_a) {
  const int ng = (m + 1) >> 1;
  for (int g = threadIdx.x; g < ng; g += WV_THREADS) {
    float w[10];
    if (g >= 2 && 4 * g + 9 <= n + 5) {
      const float2* af = (const float2*)a + (2 * g - 3);
      float2 b0 = af[0], b1 = af[1], b2 = af[2], b3 = af[3], b4 = af[4];
      w[0] = b0.x; w[1] = b0.y; w[2] = b1.x; w[3] = b1.y; w[4] = b2.x;
      w[5] = b2.y; w[6] = b3.x; w[7] = b3.y; w[8] = b4.x; w[9] = b4.y;
    } else {
#pragma unroll
      for (int q = 0; q < 10; ++q) {
        int j = 4 * g + q;
        int jm = n + 12;
        if (j > jm) j = jm;
        w[q] = a[ext_idx(j, n)];
      }
    }
    float sl0 = w[0]*L0 + w[1]*L1 + w[2]*L2f + w[3]*L3 + w[4]*L4 + w[5]*L5 + w[6]*L6 + w[7]*L7;
    float sh0 = w[0]*H0 + w[1]*H1 + w[2]*H2  + w[3]*H3 + w[4]*H4 + w[5]*H5 + w[6]*H6 + w[7]*H7;
    float sl1 = w[2]*L0 + w[3]*L1 + w[4]*L2f + w[5]*L3 + w[6]*L4 + w[7]*L5 + w[8]*L6 + w[9]*L7;
    float sh1 = w[2]*H0 + w[3]*H1 + w[4]*H2  + w[5]*H3 + w[6]*H4 + w[7]*H5 + w[8]*H6 + w[9]*H7;
    if (2 * g + 1 < m) {
      if (store_a) *(float2*)(anext + 2 * g) = make_float2(sl0, sl1);
      *(float2*)(d + 2 * g) = make_float2(sh0, sh1);
    } else {
      if (store_a) anext[2 * g] = sl0;
      d[2 * g] = sh0;
    }
  }
}

// one IDWT step, compile-time DLEN; 2 pairs per thread, stride-1 lanes.
template <bool HAS_CA, bool HAS_CD, bool FINAL, int DLEN>
__device__ __forceinline__ void idwt2t(const float* ca, const float* cd,
                                       float* outl, _Float16* outg) {
  constexpr int npair = DLEN - 3;
  constexpr int ng = (npair + 1) >> 1;
  constexpr bool clean = (ng % WV_THREADS) == 0;
#pragma unroll
  for (int g0 = 0; g0 < ng; g0 += WV_THREADS) {
    const int g = g0 + (int)threadIdx.x;
    if (clean || g < ng) {
      float e0 = 0.f, o0 = 0.f, e1 = 0.f, o1 = 0.f;
      if (HAS_CA) {
        const float2* f = (const float2*)ca + g;
        float2 a0 = f[0], a1 = f[1], a2 = f[2];
        e0 = a1.y*L0 + a1.x*L2f + a0.y*L4 + a0.x*L6;
        o0 = a1.y*L1 + a1.x*L3  + a0.y*L5 + a0.x*L7;
        e1 = a2.x*L0 + a1.y*L2f + a1.x*L4 + a0.y*L6;
        o1 = a2.x*L1 + a1.y*L3  + a1.x*L5 + a0.y*L7;
      }
      if (HAS_CD) {
        const float2* f = (const float2*)cd + g;
        float2 d0 = f[0], d1 = f[1], d2 = f[2];
        e0 += d1.y*H0 + d1.x*H2 + d0.y*H4 + d0.x*H6;
        o0 += d1.y*H1 + d1.x*H3 + d0.y*H5 + d0.x*H7;
        e1 += d2.x*H0 + d1.y*H2 + d1.x*H4 + d0.y*H6;
        o1 += d2.x*H1 + d1.y*H3 + d1.x*H5 + d0.y*H7;
      }
      const bool full = (2 * g + 1 < npair);
      if (FINAL) {
        if (full) {
          f16x4v h;
          h[0] = (_Float16)fmaxf(e0, 0.f); h[1] = (_Float16)fmaxf(o0, 0.f);
          h[2] = (_Float16)fmaxf(e1, 0.f); h[3] = (_Float16)fmaxf(o1, 0.f);
          *(f16x4v*)(outg + 4 * g) = h;
        } else {
          outg[4 * g]     = (_Float16)fmaxf(e0, 0.f);
          outg[4 * g + 1] = (_Float16)fmaxf(o0, 0.f);
        }
      } else {
        if (full) *(float4*)(outl + 4 * g) = make_float4(e0, o0, e1, o1);
        else      *(float2*)(outl + 4 * g) = make_float2(e0, o0);
      }
    }
  }
}

// rec_L cascade, fully specialized on L.
template <int L>
__device__ __forceinline__ void synth_cascade(const float* dr, _Float16* og,
                                              float* s1, float* s2) {
  idwt2t<false, true, false, cNL[L]>(nullptr, dr + cDOFF[L], s1, nullptr);
  __syncthreads();
  float* cur = s1;
  float* nxt = s2;
  if constexpr (L >= 3) {  // j = L-2 (with cd)
    idwt2t<true, true, false, cNL[L - 1]>(cur, dr + cDOFF[L - 1], nxt, nullptr);
    __syncthreads();
    float* t = cur; cur = nxt; nxt = t;
  }
#define NOCD_STEP(DL)                                             \
  {                                                               \
    idwt2t<true, false, false, DL>(cur, nullptr, nxt, nullptr);   \
    __syncthreads();                                              \
    float* t = cur; cur = nxt; nxt = t;                           \
  }
  if constexpr (L >= 9) NOCD_STEP(cNL[7])
  if constexpr (L >= 8) NOCD_STEP(cNL[6])
  if constexpr (L >= 7) NOCD_STEP(cNL[5])
  if constexpr (L >= 6) NOCD_STEP(cNL[4])
  if constexpr (L >= 5) NOCD_STEP(cNL[3])
  if constexpr (L >= 4) NOCD_STEP(cNL[2])
#undef NOCD_STEP
  idwt2t<true, (L == 2), true, 2051>(cur, (L == 2) ? dr + cDOFF[1] : nullptr,
                                     nullptr, og);
}

// ---------------------------------------------------------------------------
// Fused: blocks [0,2048) = analysis rows; blocks [2048, 2048+6144) = W0 cvt.
__global__ __launch_bounds__(WV_THREADS) void wv_analysis_cvt(
    const float* __restrict__ x, float* __restrict__ dG,
    const float* __restrict__ W0, _Float16* __restrict__ Bw) {
  __shared__ float r1[4104];
  __shared__ float r2[2056];
  const int tid = threadIdx.x;

  if (blockIdx.x >= 2048) {  // ---- cvt path ----
    size_t i = ((size_t)(blockIdx.x - 2048) * 256 + tid) * 4;
    int rowc = (int)(i >> 15);
    f16x4v h;
    if (rowc < 181) {
      const float4 v = *(const float4*)(W0 + i);
      h[0] = (_Float16)v.x; h[1] = (_Float16)v.y;
      h[2] = (_Float16)v.z; h[3] = (_Float16)v.w;
    } else {
      h[0] = (_Float16)0.f; h[1] = (_Float16)0.f;
      h[2] = (_Float16)0.f; h[3] = (_Float16)0.f;
    }
    *(f16x4v*)(Bw + i) = h;
    return;
  }

  const int NLa[10]  = {4096, 2051, 1029, 518, 262, 134, 70, 38, 22, 14};
  const int DOFF[10] = {0, 0, 2052, 3082, 3600, 3862, 3996, 4066, 4104, 4126};
  const int LOFF[10] = {0, 0, 1036, 520, 2068, 1040, 2332, 1176, 2404, 1216};
  const int row = blockIdx.x;

  const float4* xr = (const float4*)(x + (size_t)row * 4096);
  for (int i = tid; i < 1024; i += WV_THREADS) ((float4*)r1)[i] = xr[i];
  __syncthreads();

  float* dr = dG + (size_t)row * DROW;
  dwt2(r1, r2, dr + DOFF[1], NLa[0], NLa[1], true);
  __syncthreads();
  const float* ap = r2;
  float* an = r1;
  for (int lev = 2; lev <= 9; ++lev) {
    float* dbuf = ((lev & 1) ? r2 : r1) + LOFF[lev];
    dwt2(ap, an, dbuf, NLa[lev - 1], NLa[lev], lev < 9);
    __syncthreads();
    const float* t = ap; ap = an; an = (float*)t;
  }
  for (int lev = 2; lev <= 9; ++lev) {
    const float* src = ((lev & 1) ? r2 : r1) + LOFF[lev];
    float* dst = dr + DOFF[lev];
    const int n = NLa[lev];
    for (int i = 2 * tid; i + 1 < n; i += 2 * WV_THREADS)
      *(float2*)(dst + i) = *(const float2*)(src + i);
    if ((n & 1) && tid == 0) dst[n - 1] = src[n - 1];
  }
}

// ---------------------------------------------------------------------------
// Synthesis: one block per (row, L=2+blockIdx.y), specialized cascades.
__global__ __launch_bounds__(WV_THREADS, 6) void wv_synth(
    const float* __restrict__ dG, _Float16* __restrict__ A) {
  __shared__ float s1[2052];
  __shared__ float s2[2052];
  const int row = blockIdx.x;
  const float* dr = dG + (size_t)row * DROW;
  _Float16* og = A + (size_t)row * 32768 + (size_t)blockIdx.y * 4096;
  switch (blockIdx.y) {
    case 0: synth_cascade<2>(dr, og, s1, s2); break;
    case 1: synth_cascade<3>(dr, og, s1, s2); break;
    case 2: synth_cascade<4>(dr, og, s1, s2); break;
    case 3: synth_cascade<5>(dr, og, s1, s2); break;
    case 4: synth_cascade<6>(dr, og, s1, s2); break;
    case 5: synth_cascade<7>(dr, og, s1, s2); break;
    case 6: synth_cascade<8>(dr, og, s1, s2); break;
    default: synth_cascade<9>(dr, og, s1, s2); break;
  }
}

// ---------------------------------------------------------------------------
__device__ __forceinline__ void load_lds16(const void* g, void* l) {
  __builtin_amdgcn_global_load_lds((__attribute__((address_space(1))) unsigned int*)g,
                                   (__attribute__((address_space(3))) unsigned int*)l,
                                   16, 0, 0);
}

// C(2048x192) += A(2048x32768,f16) * Bw(192x32768,f16)^T, fp16 split-K
// partials. Grid (16 m, 64 k) = 1024 blocks = 4/CU (LDS 4x40KB = 160KB).
__global__ __launch_bounds__(256, 4) void gemm_kernel(
    const _Float16* __restrict__ A, const _Float16* __restrict__ Bw,
    _Float16* __restrict__ P) {
  __shared__ _Float16 As[128 * 64];  // 16 KB
  __shared__ _Float16 Bs[192 * 64];  // 24 KB
  const int tid = threadIdx.x;
  const int lane = tid & 63;
  const int wave = tid >> 6;
  const int m0 = blockIdx.x * 128;
  const int k_idx = blockIdx.y;
  const int k0 = k_idx * KCHUNK;

  f32x4 acc[2][12];
#pragma unroll
  for (int mt = 0; mt < 2; ++mt)
#pragma unroll
    for (int nt = 0; nt < 12; ++nt) acc[mt][nt] = (f32x4){0.f, 0.f, 0.f, 0.f};

  for (int ks = 0; ks < (KCHUNK >> 6); ++ks) {
    const int kbase = k0 + (ks << 6);
    __syncthreads();
#pragma unroll
    for (int t = 0; t < 4; ++t) {
      int g = ((wave * 4 + t) << 6) + lane;
      int r = g >> 3, cs = g & 7;
      const _Float16* gp = A + (size_t)(m0 + r) * 32768 + kbase + ((cs ^ (r & 7)) << 3);
      load_lds16(gp, (char*)As + (size_t)((wave * 4 + t) << 10));
    }
#pragma unroll
    for (int t = 0; t < 6; ++t) {
      int g = ((wave * 6 + t) << 6) + lane;
      int r = g >> 3, cs = g & 7;
      const _Float16* gp = Bw + (size_t)r * 32768 + kbase + ((cs ^ (r & 7)) << 3);
      load_lds16(gp, (char*)Bs + (size_t)((wave * 6 + t) << 10));
    }
    __syncthreads();
#pragma unroll
    for (int kk = 0; kk < 2; ++kk) {
      const int chunk = kk * 4 + (lane >> 4);
      f16x8 af[2];
#pragma unroll
      for (int mt = 0; mt < 2; ++mt) {
        int r = wave * 32 + mt * 16 + (lane & 15);
        af[mt] = *(const f16x8*)(As + r * 64 + ((chunk ^ (r & 7)) << 3));
      }
#pragma unroll
      for (int nt = 0; nt < 12; ++nt) {
        int rb = nt * 16 + (lane & 15);
        f16x8 bf = *(const f16x8*)(Bs + rb * 64 + ((chunk ^ (rb & 7)) << 3));
        acc[0][nt] = __builtin_amdgcn_mfma_f32_16x16x32_f16(af[0], bf, acc[0][nt], 0, 0, 0);
        acc[1][nt] = __builtin_amdgcn_mfma_f32_16x16x32_f16(af[1], bf, acc[1][nt], 0, 0, 0);
      }
    }
  }
  _Float16* Pp = P + ((size_t)k_idx * 2048 + m0) * 192;
#pragma unroll
  for (int mt = 0; mt < 2; ++mt)
#pragma unroll
    for (int nt = 0; nt < 12; ++nt)
#pragma unroll
      for (int r4 = 0; r4 < 4; ++r4) {
        int rr = wave * 32 + mt * 16 + ((lane >> 4) << 2) + r4;
        int cc = nt * 16 + (lane & 15);
        Pp[(size_t)rr * 192 + cc] = (_Float16)acc[mt][nt][r4];
      }
}

// ---------------------------------------------------------------------------
// P reduce (fp16 partials): 4 wave-groups x 16 splits; then layers 1..2.
__global__ __launch_bounds__(256) void mlp_kernel(
    const _Float16* __restrict__ P, const float* __restrict__ b0,
    const float* __restrict__ W1, const float* __restrict__ b1,
    const float* __restrict__ W2, const float* __restrict__ b2,
    float* __restrict__ out) {
  __shared__ float part[4][193];
  __shared__ float h1[192];
  __shared__ float h2[13];
  const int row = blockIdx.x;
  const int t = threadIdx.x;
  const int g = t >> 6;
  const int l = t & 63;

  float a0 = 0.f, a1 = 0.f, a2 = 0.f;
  for (int si = 0; si < NSPLIT / 4; ++si) {
    int s = g + (si << 2);
    const _Float16* Pr = P + ((size_t)s * 2048 + row) * 192;
    a0 += (float)Pr[l]; a1 += (float)Pr[64 + l]; a2 += (float)Pr[128 + l];
  }
  part[g][l] = a0; part[g][64 + l] = a1; part[g][128 + l] = a2;
  __syncthreads();

  if (t < 192) {
    float v = part[0][t] + part[1][t] + part[2][t] + part[3][t];
    h1[t] = (t < 181) ? fmaxf(v + b0[t], 0.f) : 0.f;
  }
  __syncthreads();

#pragma unroll
  for (int r = 0; r < 4; ++r) {
    int j = g + (r << 2);
    if (j < 13) {
      float v = 0.f;
#pragma unroll
      for (int q = 0; q < 3; ++q) {
        int n = l + (q << 6);
        if (n < 181) v += h1[n] * W1[j * 181 + n];
      }
      for (int off = 32; off >= 1; off >>= 1) v += __shfl_down(v, off);
      if (l == 0) h2[j] = fmaxf(v + b1[j], 0.f);
    }
  }
  __syncthreads();

  if (t < 10) {
    float c = b2[t];
#pragma unroll
    for (int j = 0; j < 13; ++j) c += h2[j] * W2[t * 13 + j];
    out[(size_t)row * 10 + t] = c;
  }
}

// ---------------------------------------------------------------------------
extern "C" void kernel_launch(void* const* d_in, const int* in_sizes, int n_in,
                              void* d_out, int out_size, void* d_ws, size_t ws_size,
                              hipStream_t stream) {
  const float* x1 = (const float*)d_in[0];
  const float* W0 = (const float*)d_in[3];
  const float* b0 = (const float*)d_in[4];
  const float* W1 = (const float*)d_in[5];
  const float* b1 = (const float*)d_in[6];
  const float* W2 = (const float*)d_in[7];
  const float* b2 = (const float*)d_in[8];
  float* out = (float*)d_out;

  char* ws = (char*)d_ws;
  const size_t A_BYTES = (size_t)2048 * 32768 * 2;
  const size_t B_BYTES = (size_t)192 * 32768 * 2;
  _Float16* Afeat = (_Float16*)ws;
  _Float16* Bw = (_Float16*)(ws + A_BYTES);
  // D (34 MB) aliases P (fp16, 50 MB): D dead before gemm writes P.
  float* Dq = (float*)(ws + A_BYTES + B_BYTES);
  _Float16* P = (_Float16*)(ws + A_BYTES + B_BYTES);

  wv_analysis_cvt<<<2048 + 6144, WV_THREADS, 0, stream>>>(x1, Dq, W0, Bw);
  dim3 sg(2048, 8);
  wv_synth<<<sg, WV_THREADS, 0, stream>>>(Dq, Afeat);
  dim3 gg(16, NSPLIT);
  gemm_kernel<<<gg, 256, 0, stream>>>(Afeat, Bw, P);
  mlp_kernel<<<2048, 256, 0, stream>>>(P, b0, W1, b1, W2, b2, out);
}

// Round 10
// 217.181 us; speedup vs baseline: 1.1067x; 1.1067x over previous
//
#include <hip/hip_runtime.h>
#include <hip/hip_bf16.h>

// ---------------------------------------------------------------------------
// WaveletNauralNet: 9-level DWT -> 8 band reconstructions (h: 2048x32768,
// linear in x1) -> relu -> W0 (181x32768) -> relu -> W1 (13x181) -> relu ->
// W2 (10x13).
//   K1: fused [per-row analysis (d2..d9 via LDS, single d1 drain)] +
//       [W0 fp32->fp16 convert] heterogeneous grid
//   K2: per-(row,L) synthesis; 4 pairs/thread via stride-1 float4 LDS ops
//       (R5's 16B variant used stride-32B float2 -> 8-way conflicts; this
//       form is the canonical conflict-free b128 pattern). 16B final stores.
//   K3: split-K MFMA fp16 GEMM, EXACT R8 form (BM=128,BN=192,BK=64,
//       nsplit=32, fp32 P). Floor analysis: staged bytes (A 134MB + B x16
//       m-blocks = 327MB) / 10 B/cyc/CU ~= 53us; R8 achieves ~90% of that.
//       R6 (1/CU), R7 (fp32 nsplit64), R9 (fp16 nsplit64) all regressed.
//   K4: reduce partials + MLP layers 1..2 (R8 form)
// D rows repacked: DOFF multiples of 4 (16B-aligned float4 loads), DROW 4160.
// ---------------------------------------------------------------------------

typedef _Float16 f16x8 __attribute__((ext_vector_type(8)));
typedef _Float16 f16x4v __attribute__((ext_vector_type(4)));
typedef float f32x4 __attribute__((ext_vector_type(4)));

#define WV_THREADS 256
#define DROW 4160   // per-row float stride of packed d1..d9 (16B-aligned levels)
#define NSPLIT 32
#define KCHUNK 1024

// reconstruction filters
#define L0 0.23037781330885523f
#define L1 0.7148465705525415f
#define L2f 0.6308807679295904f
#define L3 -0.02798376941698385f
#define L4 -0.18703481171888114f
#define L5 0.030841381835986965f
#define L6 0.032883011666982945f
#define L7 -0.010597401784997278f

#define H0 -0.010597401784997278f
#define H1 -0.032883011666982945f
#define H2 0.030841381835986965f
#define H3 0.18703481171888114f
#define H4 -0.02798376941698385f
#define H5 -0.6308807679295904f
#define H6 0.7148465705525415f
#define H7 -0.23037781330885523f

__constant__ constexpr int cNL[10]   = {4096, 2051, 1029, 518, 262, 134, 70, 38, 22, 14};
// 16B-aligned packing; +pad between levels absorbs float4 window over-reads
__constant__ constexpr int cDOFF[10] = {0, 0, 2052, 3084, 3604, 3868, 4004, 4076, 4116, 4140};

__device__ __forceinline__ int ext_idx(int j, int n) {
  return (j < 6) ? (5 - j) : ((j < n + 6) ? (j - 6) : (2 * n + 5 - j));
}

// one DWT level, 2 outputs per thread, stride-1 lanes.
__device__ __forceinline__ void dwt2(const float* a, float* anext, float* d,
                                     int n, int m, bool store_a) {
  const int ng = (m + 1) >> 1;
  for (int g = threadIdx.x; g < ng; g += WV_THREADS) {
    float w[10];
    if (g >= 2 && 4 * g + 9 <= n + 5) {
      const float2* af = (const float2*)a + (2 * g - 3);
      float2 b0 = af[0], b1 = af[1], b2 = af[2], b3 = af[3], b4 = af[4];
      w[0] = b0.x; w[1] = b0.y; w[2] = b1.x; w[3] = b1.y; w[4] = b2.x;
      w[5] = b2.y; w[6] = b3.x; w[7] = b3.y; w[8] = b4.x; w[9] = b4.y;
    } else {
#pragma unroll
      for (int q = 0; q < 10; ++q) {
        int j = 4 * g + q;
        int jm = n + 12;
        if (j > jm) j = jm;
        w[q] = a[ext_idx(j, n)];
      }
    }
    float sl0 = w[0]*L0 + w[1]*L1 + w[2]*L2f + w[3]*L3 + w[4]*L4 + w[5]*L5 + w[6]*L6 + w[7]*L7;
    float sh0 = w[0]*H0 + w[1]*H1 + w[2]*H2  + w[3]*H3 + w[4]*H4 + w[5]*H5 + w[6]*H6 + w[7]*H7;
    float sl1 = w[2]*L0 + w[3]*L1 + w[4]*L2f + w[5]*L3 + w[6]*L4 + w[7]*L5 + w[8]*L6 + w[9]*L7;
    float sh1 = w[2]*H0 + w[3]*H1 + w[4]*H2  + w[5]*H3 + w[6]*H4 + w[7]*H5 + w[8]*H6 + w[9]*H7;
    if (2 * g + 1 < m) {
      if (store_a) *(float2*)(anext + 2 * g) = make_float2(sl0, sl1);
      *(float2*)(d + 2 * g) = make_float2(sh0, sh1);
    } else {
      if (store_a) anext[2 * g] = sl0;
      d[2 * g] = sh0;
    }
  }
}

// one IDWT step, 4 pairs (8 outputs) per thread; stride-1 float4 reads/writes.
// e(p) = ca[p+3]L0+ca[p+2]L2+ca[p+1]L4+ca[p]L6 (+cd with H), p = 4t+q.
template <bool HAS_CA, bool HAS_CD, bool FINAL, int DLEN>
__device__ __forceinline__ void idwt4t(const float* ca, const float* cd,
                                       float* outl, _Float16* outg) {
  constexpr int npair = DLEN - 3;
  constexpr int ng4 = (npair + 3) >> 2;
#pragma unroll
  for (int t0 = 0; t0 < ng4; t0 += WV_THREADS) {
    const int t = t0 + (int)threadIdx.x;
    if (t < ng4) {
      float w[8], v[8];
      if (HAS_CA) {
        float4 A4 = ((const float4*)ca)[t];
        float4 B4 = ((const float4*)ca)[t + 1];
        w[0]=A4.x; w[1]=A4.y; w[2]=A4.z; w[3]=A4.w;
        w[4]=B4.x; w[5]=B4.y; w[6]=B4.z; w[7]=B4.w;
      }
      if (HAS_CD) {
        float4 C4 = ((const float4*)cd)[t];
        float4 D4 = ((const float4*)cd)[t + 1];
        v[0]=C4.x; v[1]=C4.y; v[2]=C4.z; v[3]=C4.w;
        v[4]=D4.x; v[5]=D4.y; v[6]=D4.z; v[7]=D4.w;
      }
      float e[4], o[4];
#pragma unroll
      for (int q = 0; q < 4; ++q) {
        float eq = 0.f, oq = 0.f;
        if (HAS_CA) {
          eq = w[q+3]*L0 + w[q+2]*L2f + w[q+1]*L4 + w[q]*L6;
          oq = w[q+3]*L1 + w[q+2]*L3  + w[q+1]*L5 + w[q]*L7;
        }
        if (HAS_CD) {
          eq += v[q+3]*H0 + v[q+2]*H2 + v[q+1]*H4 + v[q]*H6;
          oq += v[q+3]*H1 + v[q+2]*H3 + v[q+1]*H5 + v[q]*H7;
        }
        e[q] = eq; o[q] = oq;
      }
      if (FINAL) {  // npair = 2048, divisible by 4: always full
        f16x8 h;
        h[0] = (_Float16)fmaxf(e[0], 0.f); h[1] = (_Float16)fmaxf(o[0], 0.f);
        h[2] = (_Float16)fmaxf(e[1], 0.f); h[3] = (_Float16)fmaxf(o[1], 0.f);
        h[4] = (_Float16)fmaxf(e[2], 0.f); h[5] = (_Float16)fmaxf(o[2], 0.f);
        h[6] = (_Float16)fmaxf(e[3], 0.f); h[7] = (_Float16)fmaxf(o[3], 0.f);
        *(f16x8*)(outg + 8 * t) = h;
      } else {
        if (4 * t + 3 < npair) {
          ((float4*)(outl + 8 * t))[0] = make_float4(e[0], o[0], e[1], o[1]);
          ((float4*)(outl + 8 * t))[1] = make_float4(e[2], o[2], e[3], o[3]);
        } else {
#pragma unroll
          for (int q = 0; q < 4; ++q)
            if (4 * t + q < npair)
              *(float2*)(outl + 8 * t + 2 * q) = make_float2(e[q], o[q]);
        }
      }
    }
  }
}

// rec_L cascade, fully specialized on L.
template <int L>
__device__ __forceinline__ void synth_cascade(const float* dr, _Float16* og,
                                              float* s1, float* s2) {
  idwt4t<false, true, false, cNL[L]>(nullptr, dr + cDOFF[L], s1, nullptr);
  __syncthreads();
  float* cur = s1;
  float* nxt = s2;
  if constexpr (L >= 3) {  // j = L-2 (with cd)
    idwt4t<true, true, false, cNL[L - 1]>(cur, dr + cDOFF[L - 1], nxt, nullptr);
    __syncthreads();
    float* t = cur; cur = nxt; nxt = t;
  }
#define NOCD_STEP(DL)                                             \
  {                                                               \
    idwt4t<true, false, false, DL>(cur, nullptr, nxt, nullptr);   \
    __syncthreads();                                              \
    float* t = cur; cur = nxt; nxt = t;                           \
  }
  if constexpr (L >= 9) NOCD_STEP(cNL[7])
  if constexpr (L >= 8) NOCD_STEP(cNL[6])
  if constexpr (L >= 7) NOCD_STEP(cNL[5])
  if constexpr (L >= 6) NOCD_STEP(cNL[4])
  if constexpr (L >= 5) NOCD_STEP(cNL[3])
  if constexpr (L >= 4) NOCD_STEP(cNL[2])
#undef NOCD_STEP
  idwt4t<true, (L == 2), true, 2051>(cur, (L == 2) ? dr + cDOFF[1] : nullptr,
                                     nullptr, og);
}

// ---------------------------------------------------------------------------
// Fused: blocks [0,2048) = analysis rows; blocks [2048, 2048+6144) = W0 cvt.
__global__ __launch_bounds__(WV_THREADS) void wv_analysis_cvt(
    const float* __restrict__ x, float* __restrict__ dG,
    const float* __restrict__ W0, _Float16* __restrict__ Bw) {
  __shared__ float r1[4104];
  __shared__ float r2[2056];
  const int tid = threadIdx.x;

  if (blockIdx.x >= 2048) {  // ---- cvt path ----
    size_t i = ((size_t)(blockIdx.x - 2048) * 256 + tid) * 4;
    int rowc = (int)(i >> 15);
    f16x4v h;
    if (rowc < 181) {
      const float4 v = *(const float4*)(W0 + i);
      h[0] = (_Float16)v.x; h[1] = (_Float16)v.y;
      h[2] = (_Float16)v.z; h[3] = (_Float16)v.w;
    } else {
      h[0] = (_Float16)0.f; h[1] = (_Float16)0.f;
      h[2] = (_Float16)0.f; h[3] = (_Float16)0.f;
    }
    *(f16x4v*)(Bw + i) = h;
    return;
  }

  const int NLa[10]  = {4096, 2051, 1029, 518, 262, 134, 70, 38, 22, 14};
  const int DOFF[10] = {0, 0, 2052, 3084, 3604, 3868, 4004, 4076, 4116, 4140};
  const int LOFF[10] = {0, 0, 1036, 520, 2068, 1040, 2332, 1176, 2404, 1216};
  const int row = blockIdx.x;

  const float4* xr = (const float4*)(x + (size_t)row * 4096);
  for (int i = tid; i < 1024; i += WV_THREADS) ((float4*)r1)[i] = xr[i];
  __syncthreads();

  float* dr = dG + (size_t)row * DROW;
  dwt2(r1, r2, dr + DOFF[1], NLa[0], NLa[1], true);
  __syncthreads();
  const float* ap = r2;
  float* an = r1;
  for (int lev = 2; lev <= 9; ++lev) {
    float* dbuf = ((lev & 1) ? r2 : r1) + LOFF[lev];
    dwt2(ap, an, dbuf, NLa[lev - 1], NLa[lev], lev < 9);
    __syncthreads();
    const float* t = ap; ap = an; an = (float*)t;
  }
  for (int lev = 2; lev <= 9; ++lev) {
    const float* src = ((lev & 1) ? r2 : r1) + LOFF[lev];
    float* dst = dr + DOFF[lev];
    const int n = NLa[lev];
    for (int i = 2 * tid; i + 1 < n; i += 2 * WV_THREADS)
      *(float2*)(dst + i) = *(const float2*)(src + i);
    if ((n & 1) && tid == 0) dst[n - 1] = src[n - 1];
  }
}

// ---------------------------------------------------------------------------
// Synthesis: one block per (row, L=2+blockIdx.y), specialized cascades.
__global__ __launch_bounds__(WV_THREADS, 6) void wv_synth(
    const float* __restrict__ dG, _Float16* __restrict__ A) {
  __shared__ float s1[2052];
  __shared__ float s2[2052];
  const int row = blockIdx.x;
  const float* dr = dG + (size_t)row * DROW;
  _Float16* og = A + (size_t)row * 32768 + (size_t)blockIdx.y * 4096;
  switch (blockIdx.y) {
    case 0: synth_cascade<2>(dr, og, s1, s2); break;
    case 1: synth_cascade<3>(dr, og, s1, s2); break;
    case 2: synth_cascade<4>(dr, og, s1, s2); break;
    case 3: synth_cascade<5>(dr, og, s1, s2); break;
    case 4: synth_cascade<6>(dr, og, s1, s2); break;
    case 5: synth_cascade<7>(dr, og, s1, s2); break;
    case 6: synth_cascade<8>(dr, og, s1, s2); break;
    default: synth_cascade<9>(dr, og, s1, s2); break;
  }
}

// ---------------------------------------------------------------------------
__device__ __forceinline__ void load_lds16(const void* g, void* l) {
  __builtin_amdgcn_global_load_lds((__attribute__((address_space(1))) unsigned int*)g,
                                   (__attribute__((address_space(3))) unsigned int*)l,
                                   16, 0, 0);
}

// C(2048x192) += A(2048x32768,f16) * Bw(192x32768,f16)^T, fp32 split-K
// partials. Grid (16 m, 32 k) = 512 blocks = 2/CU. (Exact R8 form.)
__global__ __launch_bounds__(256, 2) void gemm_kernel(
    const _Float16* __restrict__ A, const _Float16* __restrict__ Bw,
    float* __restrict__ P) {
  __shared__ _Float16 As[128 * 64];  // 16 KB
  __shared__ _Float16 Bs[192 * 64];  // 24 KB
  const int tid = threadIdx.x;
  const int lane = tid & 63;
  const int wave = tid >> 6;
  const int m0 = blockIdx.x * 128;
  const int k_idx = blockIdx.y;
  const int k0 = k_idx * KCHUNK;

  f32x4 acc[2][12];
#pragma unroll
  for (int mt = 0; mt < 2; ++mt)
#pragma unroll
    for (int nt = 0; nt < 12; ++nt) acc[mt][nt] = (f32x4){0.f, 0.f, 0.f, 0.f};

  for (int ks = 0; ks < (KCHUNK >> 6); ++ks) {
    const int kbase = k0 + (ks << 6);
    __syncthreads();
#pragma unroll
    for (int t = 0; t < 4; ++t) {
      int g = ((wave * 4 + t) << 6) + lane;
      int r = g >> 3, cs = g & 7;
      const _Float16* gp = A + (size_t)(m0 + r) * 32768 + kbase + ((cs ^ (r & 7)) << 3);
      load_lds16(gp, (char*)As + (size_t)((wave * 4 + t) << 10));
    }
#pragma unroll
    for (int t = 0; t < 6; ++t) {
      int g = ((wave * 6 + t) << 6) + lane;
      int r = g >> 3, cs = g & 7;
      const _Float16* gp = Bw + (size_t)r * 32768 + kbase + ((cs ^ (r & 7)) << 3);
      load_lds16(gp, (char*)Bs + (size_t)((wave * 6 + t) << 10));
    }
    __syncthreads();
#pragma unroll
    for (int kk = 0; kk < 2; ++kk) {
      const int chunk = kk * 4 + (lane >> 4);
      f16x8 af[2];
#pragma unroll
      for (int mt = 0; mt < 2; ++mt) {
        int r = wave * 32 + mt * 16 + (lane & 15);
        af[mt] = *(const f16x8*)(As + r * 64 + ((chunk ^ (r & 7)) << 3));
      }
#pragma unroll
      for (int nt = 0; nt < 12; ++nt) {
        int rb = nt * 16 + (lane & 15);
        f16x8 bf = *(const f16x8*)(Bs + rb * 64 + ((chunk ^ (rb & 7)) << 3));
        acc[0][nt] = __builtin_amdgcn_mfma_f32_16x16x32_f16(af[0], bf, acc[0][nt], 0, 0, 0);
        acc[1][nt] = __builtin_amdgcn_mfma_f32_16x16x32_f16(af[1], bf, acc[1][nt], 0, 0, 0);
      }
    }
  }
  float* Pp = P + ((size_t)k_idx * 2048 + m0) * 192;
#pragma unroll
  for (int mt = 0; mt < 2; ++mt)
#pragma unroll
    for (int nt = 0; nt < 12; ++nt)
#pragma unroll
      for (int r4 = 0; r4 < 4; ++r4) {
        int rr = wave * 32 + mt * 16 + ((lane >> 4) << 2) + r4;
        int cc = nt * 16 + (lane & 15);
        Pp[(size_t)rr * 192 + cc] = acc[mt][nt][r4];
      }
}

// ---------------------------------------------------------------------------
// P reduce: 4 wave-groups x 8 splits, coalesced; then layers 1..2. (R8 form.)
__global__ __launch_bounds__(256) void mlp_kernel(
    const float* __restrict__ P, const float* __restrict__ b0,
    const float* __restrict__ W1, const float* __restrict__ b1,
    const float* __restrict__ W2, const float* __restrict__ b2,
    float* __restrict__ out) {
  __shared__ float part[4][193];
  __shared__ float h1[192];
  __shared__ float h2[13];
  const int row = blockIdx.x;
  const int t = threadIdx.x;
  const int g = t >> 6;
  const int l = t & 63;

  float a0 = 0.f, a1 = 0.f, a2 = 0.f;
  for (int si = 0; si < NSPLIT / 4; ++si) {
    int s = g + (si << 2);
    const float* Pr = P + ((size_t)s * 2048 + row) * 192;
    a0 += Pr[l]; a1 += Pr[64 + l]; a2 += Pr[128 + l];
  }
  part[g][l] = a0; part[g][64 + l] = a1; part[g][128 + l] = a2;
  __syncthreads();

  if (t < 192) {
    float v = part[0][t] + part[1][t] + part[2][t] + part[3][t];
    h1[t] = (t < 181) ? fmaxf(v + b0[t], 0.f) : 0.f;
  }
  __syncthreads();

#pragma unroll
  for (int r = 0; r < 4; ++r) {
    int j = g + (r << 2);
    if (j < 13) {
      float v = 0.f;
#pragma unroll
      for (int q = 0; q < 3; ++q) {
        int n = l + (q << 6);
        if (n < 181) v += h1[n] * W1[j * 181 + n];
      }
      for (int off = 32; off >= 1; off >>= 1) v += __shfl_down(v, off);
      if (l == 0) h2[j] = fmaxf(v + b1[j], 0.f);
    }
  }
  __syncthreads();

  if (t < 10) {
    float c = b2[t];
#pragma unroll
    for (int j = 0; j < 13; ++j) c += h2[j] * W2[t * 13 + j];
    out[(size_t)row * 10 + t] = c;
  }
}

// ---------------------------------------------------------------------------
extern "C" void kernel_launch(void* const* d_in, const int* in_sizes, int n_in,
                              void* d_out, int out_size, void* d_ws, size_t ws_size,
                              hipStream_t stream) {
  const float* x1 = (const float*)d_in[0];
  const float* W0 = (const float*)d_in[3];
  const float* b0 = (const float*)d_in[4];
  const float* W1 = (const float*)d_in[5];
  const float* b1 = (const float*)d_in[6];
  const float* W2 = (const float*)d_in[7];
  const float* b2 = (const float*)d_in[8];
  float* out = (float*)d_out;

  char* ws = (char*)d_ws;
  const size_t A_BYTES = (size_t)2048 * 32768 * 2;
  const size_t B_BYTES = (size_t)192 * 32768 * 2;
  _Float16* Afeat = (_Float16*)ws;
  _Float16* Bw = (_Float16*)(ws + A_BYTES);
  // D (2048*4160*4 = 34 MB) aliases P (50 MB): D dead before gemm writes P.
  float* Dq = (float*)(ws + A_BYTES + B_BYTES);
  float* P = (float*)(ws + A_BYTES + B_BYTES);

  wv_analysis_cvt<<<2048 + 6144, WV_THREADS, 0, stream>>>(x1, Dq, W0, Bw);
  dim3 sg(2048, 8);
  wv_synth<<<sg, WV_THREADS, 0, stream>>>(Dq, Afeat);
  dim3 gg(16, NSPLIT);
  gemm_kernel<<<gg, 256, 0, stream>>>(Afeat, Bw, P);
  mlp_kernel<<<2048, 256, 0, stream>>>(P, b0, W1, b1, W2, b2, out);
}